// Round 15
// baseline (172.666 us; speedup 1.0000x reference)
//
#include <hip/hip_runtime.h>

#define DEVI __device__ __forceinline__

typedef short bf16x8 __attribute__((ext_vector_type(8)));
typedef float f32x4 __attribute__((ext_vector_type(4)));
typedef unsigned short u16;
typedef unsigned int u32;

// Problem constants
static constexpr int Bn = 2, S = 2048, E = 1024, H = 16, D = 64;
static constexpr int Mrows = Bn * S;          // 4096
static constexpr int N_QKV = 3 * E;           // 3072

DEVI u16 f2b(float f) {
  union { float f; u32 u; } c; c.f = f;
  return (u16)((c.u + 0x7FFFu + ((c.u >> 16) & 1u)) >> 16);
}

DEVI bf16x8 ld8(const u16* p) {
  union { uint4 u; bf16x8 v; } c;
  c.u = *reinterpret_cast<const uint4*>(p);
  return c.v;
}

#define MFMA(a, b, c) __builtin_amdgcn_mfma_f32_16x16x32_bf16(a, b, c, 0, 0, 0)

// global -> LDS async copy, 16B per lane. LDS dest must be wave-uniform-base + lane*16.
#define G2L16(gptr, lptr) \
  __builtin_amdgcn_global_load_lds((const __attribute__((address_space(1))) void*)(gptr), \
                                   (__attribute__((address_space(3))) void*)(lptr), 16, 0, 0)

// ---------------- Fused prep: transposes FIRST, conv LAST (r14 order) ----------------
__global__ __launch_bounds__(256) void prep(const float* __restrict__ x,
                                            const float* __restrict__ w_attn,
                                            const float* __restrict__ w_proj,
                                            u16* __restrict__ xb, u16* __restrict__ wabT,
                                            u16* __restrict__ wpbT) {
  __shared__ float t[32][33];
  int blk = blockIdx.x, tid = threadIdx.x;
  if (blk >= 4096) {
    int i = (blk - 4096) * 256 + tid;          // n4 = 4096*1024/4 = 1048576
    float4 f = reinterpret_cast<const float4*>(x)[i];
    ushort4 u;
    u.x = f2b(f.x); u.y = f2b(f.y); u.z = f2b(f.z); u.w = f2b(f.w);
    reinterpret_cast<ushort4*>(xb)[i] = u;
    return;
  }
  const float* in; u16* out; int R, C, bx, by;
  if (blk < 3072) {
    in = w_attn; out = wabT; R = E; C = N_QKV;  // 96 x 32 tiles
    bx = (blk % 96) * 32; by = (blk / 96) * 32;
  } else {
    int q = blk - 3072;                         // 32 x 32 tiles
    in = w_proj; out = wpbT; R = E; C = E;
    bx = (q % 32) * 32; by = (q / 32) * 32;
  }
  int tx = tid & 31, ty = tid >> 5;             // 32 x 8
#pragma unroll
  for (int k = 0; k < 32; k += 8)
    t[ty + k][tx] = in[(size_t)(by + ty + k) * C + bx + tx];
  __syncthreads();
#pragma unroll
  for (int k = 0; k < 32; k += 8)
    out[(size_t)(bx + ty + k) * R + by + tx] = f2b(t[tx][ty + k]);
}

// ---------------- GEMM1: qkv = xb @ wabT^T, 128x64 tile, BK=64, XOR swizzle (r14) ---------
// Q pre-scaled by log2e/8 so attn scores arrive in log2 domain (exp2 = bare v_exp_f32).
__global__ __launch_bounds__(256) void gemm_qkv(const u16* __restrict__ A, const u16* __restrict__ BT,
                                                u16* __restrict__ Qb, u16* __restrict__ Kb,
                                                u16* __restrict__ VbT) {
  constexpr int K = 1024, BK = 64;
  __shared__ __align__(16) u16 As[128 * BK];   // 16 KB, swizzled rows of 8 16B-groups
  __shared__ __align__(16) u16 Bs[64 * BK];    // 8 KB
  int tid = threadIdx.x;
  int w = tid >> 6, lane = tid & 63, quad = lane >> 4, l15 = lane & 15;
  int m0 = blockIdx.x * 128, n0 = blockIdx.y * 64;
  int mw = (w >> 1) * 64, nw = (w & 1) * 32;   // wave-tile 64x32
  const u16* Ab = A + (size_t)m0 * K;
  const u16* Bb = BT + (size_t)n0 * K;
  f32x4 acc[4][2] = {};
  for (int k0 = 0; k0 < K; k0 += BK) {
#pragma unroll
    for (int j = 0; j < 4; j++) {
      int L = j * 256 + tid;
      int row = L >> 3, cg = (L & 7) ^ (row & 7);
      G2L16(Ab + (size_t)row * K + k0 + cg * 8, (char*)As + L * 16);
    }
#pragma unroll
    for (int j = 0; j < 2; j++) {
      int L = j * 256 + tid;
      int row = L >> 3, cg = (L & 7) ^ (row & 7);
      G2L16(Bb + (size_t)row * K + k0 + cg * 8, (char*)Bs + L * 16);
    }
    __syncthreads();
#pragma unroll
    for (int kk = 0; kk < 2; kk++) {
      int sg = ((kk << 2) | quad) ^ (l15 & 7);   // swizzled 16B-group for this lane
      bf16x8 a[4], b[2];
#pragma unroll
      for (int i = 0; i < 4; i++) a[i] = ld8(&As[(mw + i * 16 + l15) * BK + sg * 8]);
#pragma unroll
      for (int i = 0; i < 2; i++) b[i] = ld8(&Bs[(nw + i * 16 + l15) * BK + sg * 8]);
#pragma unroll
      for (int mb = 0; mb < 4; mb++)
#pragma unroll
        for (int nb = 0; nb < 2; nb++)
          acc[mb][nb] = MFMA(a[mb], b[nb], acc[mb][nb]);
    }
    __syncthreads();
  }
#pragma unroll
  for (int mb = 0; mb < 4; mb++) {
    int m = m0 + mw + mb * 16 + quad * 4;      // rows m..m+3 (tiles never straddle batch)
    int b = m >> 11, s = m & 2047;
#pragma unroll
    for (int nb = 0; nb < 2; nb++) {
      int n = n0 + nw + nb * 16 + l15;
      int sec = n >> 10, e = n & 1023, h = e >> 6, d = e & 63;
      int bh = b * H + h;
      if (sec == 0) {
#pragma unroll
        for (int r = 0; r < 4; r++)
          Qb[((size_t)bh * S + s + r) * D + d] = f2b(acc[mb][nb][r] * 0.1803368801111244f);
      } else if (sec == 1) {
#pragma unroll
        for (int r = 0; r < 4; r++)
          Kb[((size_t)bh * S + s + r) * D + d] = f2b(acc[mb][nb][r]);
      } else {
        ushort4 v;
        v.x = f2b(acc[mb][nb][0]); v.y = f2b(acc[mb][nb][1]);
        v.z = f2b(acc[mb][nb][2]); v.w = f2b(acc[mb][nb][3]);
        *reinterpret_cast<ushort4*>(VbT + ((size_t)bh * D + d) * S + s) = v;
      }
    }
  }
}

// ---------------- Flash attention: merged paired q-tiles + lean softmax tail --------------
// VALU diet vs r9: scores arrive log2-scaled (Q pre-scaled by log2e/8) -> exp2f is one
// v_exp_f32; bf16 pair-pack via v_perm_b32 with round-half-up (+0x8000) -- 3 ops/pair
// vs ~10 for manual RNE. Inner-loop VALU per 16-key subtile: ~30 -> ~13 ops.
__global__ __launch_bounds__(256, 3) void attn(const u16* __restrict__ Qb, const u16* __restrict__ Kb,
                                               const u16* __restrict__ VbT, u16* __restrict__ Yb) {
  __shared__ __align__(16) u16 Ks[128 * 64];    // swizzled: (row, cg) at row*64 + (cg^(row&7))*8
  __shared__ __align__(16) u16 Vs[64 * 128];    // swizzled: (d, cg) at d*128 + (cg^(d&15))*8
  __shared__ __align__(16) u32 Ps[4][16 * 68];  // per-wave P[q=16][k=128] bf16, row stride 68 u32
  int w = threadIdx.x >> 6, lane = threadIdx.x & 63, quad = lane >> 4, l15 = lane & 15;
  int bh = blockIdx.x & 31, p = blockIdx.x >> 5;   // p in [0,16)
  int b = bh >> 4, h = bh & 15;
  int qtA = 31 - p, qtB = p;
  int ncA = (qtA + 2) >> 1, ncB = (qtB + 2) >> 1;  // staged chunks needed per tile

  const u16* Kbh = Kb + (size_t)bh * S * D;
  const u16* Vbh = VbT + (size_t)bh * D * S;
  u32* myP = &Ps[w][0];
  const u16* myP16 = (const u16*)myP;
  int prow = l15 * 68 + quad * 2;    // u32 index for this lane's P writes

  int qbA = qtA * 64 + w * 16, qbB = qtB * 64 + w * 16;
  int kmaxA = qbA + 16, kmaxB = qbB + 16;
  const u16* QpA = Qb + ((size_t)bh * S + qbA + l15) * D + quad * 8;
  const u16* QpB = Qb + ((size_t)bh * S + qbB + l15) * D + quad * 8;
  bf16x8 bqA0 = ld8(QpA), bqA1 = ld8(QpA + 32);
  bf16x8 bqB0 = ld8(QpB), bqB1 = ld8(QpB + 32);

  float lA = 0.f, lB = 0.f;
  f32x4 oA[4] = {}, oB[4] = {};
  int kbase = 0;

  auto process = [&](int q_base, int kmaxW, bf16x8 bq0, bf16x8 bq1, f32x4* o, float& lpart) {
    // ---- QK^T + exp2 + perm-pack into wave-private P ----
#pragma unroll
    for (int mb = 0; mb < 8; mb++) {
      int kb = kbase + mb * 16;
      u32 pa = 0, pb = 0;
      if (kb < kmaxW) {              // wave-uniform
        int row = mb * 16 + l15;
        bf16x8 ak0 = ld8(&Ks[row * 64 + ((quad ^ (row & 7)) * 8)]);
        bf16x8 ak1 = ld8(&Ks[row * 64 + (((quad + 4) ^ (row & 7)) * 8)]);
        f32x4 z = {};
        z = MFMA(ak0, bq0, z);
        z = MFMA(ak1, bq1, z);
        if (kb == q_base) {          // diagonal subtile: mask k > q
#pragma unroll
          for (int r = 0; r < 4; r++)
            if (quad * 4 + r > l15) z[r] = -1e30f;
        }
        float p0 = __builtin_amdgcn_exp2f(z[0]);
        float p1 = __builtin_amdgcn_exp2f(z[1]);
        float p2 = __builtin_amdgcn_exp2f(z[2]);
        float p3 = __builtin_amdgcn_exp2f(z[3]);
        lpart += (p0 + p1) + (p2 + p3);
        union { float f; u32 u; } c0, c1, c2, c3;
        c0.f = p0; c1.f = p1; c2.f = p2; c3.f = p3;
        // pack bf16 pair: low16 = rnd(p0), high16 = rnd(p1); round-half-up via +0x8000
        pa = __builtin_amdgcn_perm(c1.u + 0x8000u, c0.u + 0x8000u, 0x07060302u);
        pb = __builtin_amdgcn_perm(c3.u + 0x8000u, c2.u + 0x8000u, 0x07060302u);
      }
      uint2 pw; pw.x = pa; pw.y = pb;
      *reinterpret_cast<uint2*>(&myP[prow + mb * 8]) = pw;   // ds_write_b64
    }
    // ---- O^T += V^T · P^T per 32-key chunk ----
#pragma unroll
    for (int ch = 0; ch < 4; ch++) {
      if (kbase + ch * 32 < kmaxW) { // wave-uniform
        bf16x8 bp = ld8(myP16 + l15 * 136 + ch * 32 + quad * 8);
#pragma unroll
        for (int dd = 0; dd < 4; dd++) {
          int rv = dd * 16 + l15;
          bf16x8 av = ld8(&Vs[rv * 128 + (((ch * 4 + quad) ^ (rv & 15)) * 8)]);
          o[dd] = MFMA(av, bp, o[dd]);
        }
      }
    }
  };

  for (int c = 0; c < ncA; c++) {
    kbase = c * 128;
    __syncthreads();               // previous chunk's readers done
    // ---- cooperative staging: K tile (16KB) ----
    const u16* Kg = Kbh + (size_t)kbase * D;
#pragma unroll
    for (int j = 0; j < 4; j++) {
      int L = (w * 4 + j) * 64 + lane;
      int row = L >> 3, cg = (L & 7) ^ (row & 7);
      G2L16(Kg + (size_t)row * 64 + cg * 8, (char*)Ks + L * 16);
    }
    // ---- cooperative staging: V^T tile (16KB) ----
    const u16* Vg = Vbh + kbase;
#pragma unroll
    for (int j = 0; j < 4; j++) {
      int L = (w * 4 + j) * 64 + lane;
      int row = L >> 4, cg = (L & 15) ^ (row & 15);
      G2L16(Vg + (size_t)row * S + cg * 8, (char*)Vs + L * 16);
    }
    __syncthreads();               // staging visible (barrier drains vmcnt)

    process(qbA, kmaxA, bqA0, bqA1, oA, lA);
    if (c < ncB)                   // block-uniform
      process(qbB, kmaxB, bqB0, bqB1, oB, lB);
  }

  // ---- epilogues: each wave owns the full k-range of its 16 q-rows ----
  {
    float l = lA; l += __shfl_xor(l, 16); l += __shfl_xor(l, 32);
    float rinv = 1.0f / l;
    u16* Yp = Yb + ((size_t)b * S + qbA + l15) * E + h * 64 + quad * 4;
#pragma unroll
    for (int dd = 0; dd < 4; dd++) {
      ushort4 y;
      y.x = f2b(oA[dd][0] * rinv); y.y = f2b(oA[dd][1] * rinv);
      y.z = f2b(oA[dd][2] * rinv); y.w = f2b(oA[dd][3] * rinv);
      *reinterpret_cast<ushort4*>(Yp + dd * 16) = y;
    }
  }
  {
    float l = lB; l += __shfl_xor(l, 16); l += __shfl_xor(l, 32);
    float rinv = 1.0f / l;
    u16* Yp = Yb + ((size_t)b * S + qbB + l15) * E + h * 64 + quad * 4;
#pragma unroll
    for (int dd = 0; dd < 4; dd++) {
      ushort4 y;
      y.x = f2b(oB[dd][0] * rinv); y.y = f2b(oB[dd][1] * rinv);
      y.z = f2b(oB[dd][2] * rinv); y.w = f2b(oB[dd][3] * rinv);
      *reinterpret_cast<ushort4*>(Yp + dd * 16) = y;
    }
  }
}

// ---------------- GEMM2: out = Yb @ wpbT^T, 128x64 tile (512 blocks = 2/CU), fp32 out ----
__global__ __launch_bounds__(256) void gemm_proj(const u16* __restrict__ A, const u16* __restrict__ BT,
                                                 float* __restrict__ out) {
  constexpr int K = 1024, BK = 64;
  __shared__ __align__(16) u16 As[128 * BK];   // 16 KB
  __shared__ __align__(16) u16 Bs[64 * BK];    // 8 KB
  int tid = threadIdx.x;
  int w = tid >> 6, lane = tid & 63, quad = lane >> 4, l15 = lane & 15;
  int m0 = blockIdx.x * 128, n0 = blockIdx.y * 64;
  int mw = (w >> 1) * 64, nw = (w & 1) * 32;
  const u16* Ab = A + (size_t)m0 * K;
  const u16* Bb = BT + (size_t)n0 * K;
  f32x4 acc[4][2] = {};
  for (int k0 = 0; k0 < K; k0 += BK) {
#pragma unroll
    for (int j = 0; j < 4; j++) {
      int L = j * 256 + tid;
      int row = L >> 3, cg = (L & 7) ^ (row & 7);
      G2L16(Ab + (size_t)row * K + k0 + cg * 8, (char*)As + L * 16);
    }
#pragma unroll
    for (int j = 0; j < 2; j++) {
      int L = j * 256 + tid;
      int row = L >> 3, cg = (L & 7) ^ (row & 7);
      G2L16(Bb + (size_t)row * K + k0 + cg * 8, (char*)Bs + L * 16);
    }
    __syncthreads();
#pragma unroll
    for (int kk = 0; kk < 2; kk++) {
      int sg = ((kk << 2) | quad) ^ (l15 & 7);
      bf16x8 a[4], b[2];
#pragma unroll
      for (int i = 0; i < 4; i++) a[i] = ld8(&As[(mw + i * 16 + l15) * BK + sg * 8]);
#pragma unroll
      for (int i = 0; i < 2; i++) b[i] = ld8(&Bs[(nw + i * 16 + l15) * BK + sg * 8]);
#pragma unroll
      for (int mb = 0; mb < 4; mb++)
#pragma unroll
        for (int nb = 0; nb < 2; nb++)
          acc[mb][nb] = MFMA(a[mb], b[nb], acc[mb][nb]);
    }
    __syncthreads();
  }
#pragma unroll
  for (int mb = 0; mb < 4; mb++) {
    int m = m0 + mw + mb * 16 + quad * 4;
#pragma unroll
    for (int nb = 0; nb < 2; nb++) {
      int n = n0 + nw + nb * 16 + l15;
#pragma unroll
      for (int r = 0; r < 4; r++)
        out[(size_t)(m + r) * E + n] = acc[mb][nb][r];
    }
  }
}

extern "C" void kernel_launch(void* const* d_in, const int* in_sizes, int n_in,
                              void* d_out, int out_size, void* d_ws, size_t ws_size,
                              hipStream_t stream) {
  const float* x = (const float*)d_in[0];
  const float* w_attn = (const float*)d_in[1];
  const float* w_proj = (const float*)d_in[2];
  float* out = (float*)d_out;
  char* ws = (char*)d_ws;

  // workspace layout (bytes)
  u16* xb   = (u16*)(ws);                      // 4096*1024*2 = 8 MB
  u16* wabT = (u16*)(ws + 8388608);            // 3072*1024*2 = 6 MB
  u16* wpbT = (u16*)(ws + 14680064);           // 1024*1024*2 = 2 MB
  u16* Qb   = (u16*)(ws + 16777216);           // 8 MB
  u16* Kb   = (u16*)(ws + 25165824);           // 8 MB
  u16* VbT  = (u16*)(ws + 33554432);           // 8 MB
  u16* Yb   = (u16*)(ws + 41943040);           // 8 MB   (total 48 MB)

  prep<<<8192, 256, 0, stream>>>(x, w_attn, w_proj, xb, wabT, wpbT);
  gemm_qkv<<<dim3(Mrows / 128, N_QKV / 64), 256, 0, stream>>>(xb, wabT, Qb, Kb, VbT);
  attn<<<Bn * H * (S / 128), 256, 0, stream>>>(Qb, Kb, VbT, Yb);
  gemm_proj<<<dim3(Mrows / 128, E / 64), 256, 0, stream>>>(Yb, wpbT, out);
}

// Round 16
// 167.946 us; speedup vs baseline: 1.0281x; 1.0281x over previous
//
#include <hip/hip_runtime.h>

#define DEVI __device__ __forceinline__

typedef short bf16x8 __attribute__((ext_vector_type(8)));
typedef float f32x4 __attribute__((ext_vector_type(4)));
typedef unsigned short u16;
typedef unsigned int u32;

// Problem constants
static constexpr int Bn = 2, S = 2048, E = 1024, H = 16, D = 64;
static constexpr int Mrows = Bn * S;          // 4096
static constexpr int N_QKV = 3 * E;           // 3072

DEVI u16 f2b(float f) {
  union { float f; u32 u; } c; c.f = f;
  return (u16)((c.u + 0x7FFFu + ((c.u >> 16) & 1u)) >> 16);
}

DEVI bf16x8 ld8(const u16* p) {
  union { uint4 u; bf16x8 v; } c;
  c.u = *reinterpret_cast<const uint4*>(p);
  return c.v;
}

#define MFMA(a, b, c) __builtin_amdgcn_mfma_f32_16x16x32_bf16(a, b, c, 0, 0, 0)

// global -> LDS async copy, 16B per lane. LDS dest must be wave-uniform-base + lane*16.
#define G2L16(gptr, lptr) \
  __builtin_amdgcn_global_load_lds((const __attribute__((address_space(1))) void*)(gptr), \
                                   (__attribute__((address_space(3))) void*)(lptr), 16, 0, 0)

// ---------------- Fused prep: transposes FIRST, conv LAST (r14 order) ----------------
__global__ __launch_bounds__(256) void prep(const float* __restrict__ x,
                                            const float* __restrict__ w_attn,
                                            const float* __restrict__ w_proj,
                                            u16* __restrict__ xb, u16* __restrict__ wabT,
                                            u16* __restrict__ wpbT) {
  __shared__ float t[32][33];
  int blk = blockIdx.x, tid = threadIdx.x;
  if (blk >= 4096) {
    int i = (blk - 4096) * 256 + tid;          // n4 = 4096*1024/4 = 1048576
    float4 f = reinterpret_cast<const float4*>(x)[i];
    ushort4 u;
    u.x = f2b(f.x); u.y = f2b(f.y); u.z = f2b(f.z); u.w = f2b(f.w);
    reinterpret_cast<ushort4*>(xb)[i] = u;
    return;
  }
  const float* in; u16* out; int R, C, bx, by;
  if (blk < 3072) {
    in = w_attn; out = wabT; R = E; C = N_QKV;  // 96 x 32 tiles
    bx = (blk % 96) * 32; by = (blk / 96) * 32;
  } else {
    int q = blk - 3072;                         // 32 x 32 tiles
    in = w_proj; out = wpbT; R = E; C = E;
    bx = (q % 32) * 32; by = (q / 32) * 32;
  }
  int tx = tid & 31, ty = tid >> 5;             // 32 x 8
#pragma unroll
  for (int k = 0; k < 32; k += 8)
    t[ty + k][tx] = in[(size_t)(by + ty + k) * C + bx + tx];
  __syncthreads();
#pragma unroll
  for (int k = 0; k < 32; k += 8)
    out[(size_t)(bx + ty + k) * R + by + tx] = f2b(t[tx][ty + k]);
}

// ---------------- GEMM1: qkv = xb @ wabT^T, 128x64 tile, BK=64, XOR swizzle (r14) ---------
// Q pre-scaled by log2e/8 so attn scores arrive in log2 domain (exp2 = bare v_exp_f32).
__global__ __launch_bounds__(256) void gemm_qkv(const u16* __restrict__ A, const u16* __restrict__ BT,
                                                u16* __restrict__ Qb, u16* __restrict__ Kb,
                                                u16* __restrict__ VbT) {
  constexpr int K = 1024, BK = 64;
  __shared__ __align__(16) u16 As[128 * BK];   // 16 KB, swizzled rows of 8 16B-groups
  __shared__ __align__(16) u16 Bs[64 * BK];    // 8 KB
  int tid = threadIdx.x;
  int w = tid >> 6, lane = tid & 63, quad = lane >> 4, l15 = lane & 15;
  int m0 = blockIdx.x * 128, n0 = blockIdx.y * 64;
  int mw = (w >> 1) * 64, nw = (w & 1) * 32;   // wave-tile 64x32
  const u16* Ab = A + (size_t)m0 * K;
  const u16* Bb = BT + (size_t)n0 * K;
  f32x4 acc[4][2] = {};
  for (int k0 = 0; k0 < K; k0 += BK) {
#pragma unroll
    for (int j = 0; j < 4; j++) {
      int L = j * 256 + tid;
      int row = L >> 3, cg = (L & 7) ^ (row & 7);
      G2L16(Ab + (size_t)row * K + k0 + cg * 8, (char*)As + L * 16);
    }
#pragma unroll
    for (int j = 0; j < 2; j++) {
      int L = j * 256 + tid;
      int row = L >> 3, cg = (L & 7) ^ (row & 7);
      G2L16(Bb + (size_t)row * K + k0 + cg * 8, (char*)Bs + L * 16);
    }
    __syncthreads();
#pragma unroll
    for (int kk = 0; kk < 2; kk++) {
      int sg = ((kk << 2) | quad) ^ (l15 & 7);   // swizzled 16B-group for this lane
      bf16x8 a[4], b[2];
#pragma unroll
      for (int i = 0; i < 4; i++) a[i] = ld8(&As[(mw + i * 16 + l15) * BK + sg * 8]);
#pragma unroll
      for (int i = 0; i < 2; i++) b[i] = ld8(&Bs[(nw + i * 16 + l15) * BK + sg * 8]);
#pragma unroll
      for (int mb = 0; mb < 4; mb++)
#pragma unroll
        for (int nb = 0; nb < 2; nb++)
          acc[mb][nb] = MFMA(a[mb], b[nb], acc[mb][nb]);
    }
    __syncthreads();
  }
#pragma unroll
  for (int mb = 0; mb < 4; mb++) {
    int m = m0 + mw + mb * 16 + quad * 4;      // rows m..m+3 (tiles never straddle batch)
    int b = m >> 11, s = m & 2047;
#pragma unroll
    for (int nb = 0; nb < 2; nb++) {
      int n = n0 + nw + nb * 16 + l15;
      int sec = n >> 10, e = n & 1023, h = e >> 6, d = e & 63;
      int bh = b * H + h;
      if (sec == 0) {
#pragma unroll
        for (int r = 0; r < 4; r++)
          Qb[((size_t)bh * S + s + r) * D + d] = f2b(acc[mb][nb][r] * 0.1803368801111244f);
      } else if (sec == 1) {
#pragma unroll
        for (int r = 0; r < 4; r++)
          Kb[((size_t)bh * S + s + r) * D + d] = f2b(acc[mb][nb][r]);
      } else {
        ushort4 v;
        v.x = f2b(acc[mb][nb][0]); v.y = f2b(acc[mb][nb][1]);
        v.z = f2b(acc[mb][nb][2]); v.w = f2b(acc[mb][nb][3]);
        *reinterpret_cast<ushort4*>(VbT + ((size_t)bh * D + d) * S + s) = v;
      }
    }
  }
}

// ---------------- Flash attention: paired q-tiles with SHARED K/V fragments ---------------
// r15 called process() twice per chunk, re-reading identical K/V LDS frags for each
// paired tile (72 ds_read_b128/chunk/wave -- LDS pipe ~55% busy, the top consumer).
// Now one pass: each K-frag pair feeds QK MFMA for BOTH tiles (2 indep chains), each
// V-frag feeds PV for both. LDS reads/chunk: 72 -> 40. Second wave-private P buffer
// (+17KB LDS -> 67KB, still the grid-capped 2 blocks/CU).
__global__ __launch_bounds__(256, 2) void attn(const u16* __restrict__ Qb, const u16* __restrict__ Kb,
                                               const u16* __restrict__ VbT, u16* __restrict__ Yb) {
  __shared__ __align__(16) u16 Ks[128 * 64];     // swizzled: (row, cg) at row*64 + (cg^(row&7))*8
  __shared__ __align__(16) u16 Vs[64 * 128];     // swizzled: (d, cg) at d*128 + (cg^(d&15))*8
  __shared__ __align__(16) u32 PsA[4][16 * 68];  // per-wave P[q=16][k=128] bf16, stride 68 u32
  __shared__ __align__(16) u32 PsB[4][16 * 68];
  int w = threadIdx.x >> 6, lane = threadIdx.x & 63, quad = lane >> 4, l15 = lane & 15;
  int bh = blockIdx.x & 31, p = blockIdx.x >> 5;   // p in [0,16)
  int b = bh >> 4, h = bh & 15;
  int qtA = 31 - p, qtB = p;
  int ncA = (qtA + 2) >> 1, ncB = (qtB + 2) >> 1;  // staged chunks needed per tile

  const u16* Kbh = Kb + (size_t)bh * S * D;
  const u16* Vbh = VbT + (size_t)bh * D * S;
  u32* myPA = &PsA[w][0];
  u32* myPB = &PsB[w][0];
  const u16* myPA16 = (const u16*)myPA;
  const u16* myPB16 = (const u16*)myPB;
  int prow = l15 * 68 + quad * 2;    // u32 index for this lane's P writes

  int qbA = qtA * 64 + w * 16, qbB = qtB * 64 + w * 16;
  int kmaxA = qbA + 16, kmaxB = qbB + 16;   // kmaxB < kmaxA always (p < 16)
  const u16* QpA = Qb + ((size_t)bh * S + qbA + l15) * D + quad * 8;
  const u16* QpB = Qb + ((size_t)bh * S + qbB + l15) * D + quad * 8;
  bf16x8 bqA0 = ld8(QpA), bqA1 = ld8(QpA + 32);
  bf16x8 bqB0 = ld8(QpB), bqB1 = ld8(QpB + 32);

  float lA = 0.f, lB = 0.f;
  f32x4 oA[4] = {}, oB[4] = {};

  for (int c = 0; c < ncA; c++) {
    int kbase = c * 128;
    bool doB = (c < ncB);            // block-uniform
    __syncthreads();                 // previous chunk's readers done
    // ---- cooperative staging: K tile (16KB) ----
    const u16* Kg = Kbh + (size_t)kbase * D;
#pragma unroll
    for (int j = 0; j < 4; j++) {
      int L = (w * 4 + j) * 64 + lane;
      int row = L >> 3, cg = (L & 7) ^ (row & 7);
      G2L16(Kg + (size_t)row * 64 + cg * 8, (char*)Ks + L * 16);
    }
    // ---- cooperative staging: V^T tile (16KB) ----
    const u16* Vg = Vbh + kbase;
#pragma unroll
    for (int j = 0; j < 4; j++) {
      int L = (w * 4 + j) * 64 + lane;
      int row = L >> 4, cg = (L & 15) ^ (row & 15);
      G2L16(Vg + (size_t)row * S + cg * 8, (char*)Vs + L * 16);
    }
    __syncthreads();                 // staging visible (barrier drains vmcnt)

    // ---- QK^T for BOTH tiles off one K-frag read; exp2 + perm-pack into P ----
#pragma unroll
    for (int mb = 0; mb < 8; mb++) {
      int kb = kbase + mb * 16;
      u32 pa = 0, pb = 0, pc = 0, pd = 0;
      if (kb < kmaxA) {              // wave-uniform; actB subset of actA
        int row = mb * 16 + l15;
        bf16x8 ak0 = ld8(&Ks[row * 64 + ((quad ^ (row & 7)) * 8)]);
        bf16x8 ak1 = ld8(&Ks[row * 64 + (((quad + 4) ^ (row & 7)) * 8)]);
        f32x4 zA = {};
        zA = MFMA(ak0, bqA0, zA);
        zA = MFMA(ak1, bqA1, zA);
        if (kb == qbA) {             // diagonal subtile: mask k > q
#pragma unroll
          for (int r = 0; r < 4; r++)
            if (quad * 4 + r > l15) zA[r] = -1e30f;
        }
        float a0 = __builtin_amdgcn_exp2f(zA[0]);
        float a1 = __builtin_amdgcn_exp2f(zA[1]);
        float a2 = __builtin_amdgcn_exp2f(zA[2]);
        float a3 = __builtin_amdgcn_exp2f(zA[3]);
        lA += (a0 + a1) + (a2 + a3);
        union { float f; u32 u; } u0, u1, u2, u3;
        u0.f = a0; u1.f = a1; u2.f = a2; u3.f = a3;
        pa = __builtin_amdgcn_perm(u1.u + 0x8000u, u0.u + 0x8000u, 0x07060302u);
        pb = __builtin_amdgcn_perm(u3.u + 0x8000u, u2.u + 0x8000u, 0x07060302u);
        if (doB && kb < kmaxB) {     // reuse ak0/ak1 for tile B
          f32x4 zB = {};
          zB = MFMA(ak0, bqB0, zB);
          zB = MFMA(ak1, bqB1, zB);
          if (kb == qbB) {
#pragma unroll
            for (int r = 0; r < 4; r++)
              if (quad * 4 + r > l15) zB[r] = -1e30f;
          }
          float b0 = __builtin_amdgcn_exp2f(zB[0]);
          float b1 = __builtin_amdgcn_exp2f(zB[1]);
          float b2 = __builtin_amdgcn_exp2f(zB[2]);
          float b3 = __builtin_amdgcn_exp2f(zB[3]);
          lB += (b0 + b1) + (b2 + b3);
          union { float f; u32 u; } v0, v1, v2, v3;
          v0.f = b0; v1.f = b1; v2.f = b2; v3.f = b3;
          pc = __builtin_amdgcn_perm(v1.u + 0x8000u, v0.u + 0x8000u, 0x07060302u);
          pd = __builtin_amdgcn_perm(v3.u + 0x8000u, v2.u + 0x8000u, 0x07060302u);
        }
      }
      uint2 pwA; pwA.x = pa; pwA.y = pb;
      *reinterpret_cast<uint2*>(&myPA[prow + mb * 8]) = pwA;   // ds_write_b64
      if (doB) {
        uint2 pwB; pwB.x = pc; pwB.y = pd;
        *reinterpret_cast<uint2*>(&myPB[prow + mb * 8]) = pwB; // zeros where masked
      }
    }
    // ---- PV for BOTH tiles off one V-frag read ----
#pragma unroll
    for (int ch = 0; ch < 4; ch++) {
      if (kbase + ch * 32 < kmaxA) { // wave-uniform
        bf16x8 bpA = ld8(myPA16 + l15 * 136 + ch * 32 + quad * 8);
        bf16x8 av[4];
#pragma unroll
        for (int dd = 0; dd < 4; dd++) {
          int rv = dd * 16 + l15;
          av[dd] = ld8(&Vs[rv * 128 + (((ch * 4 + quad) ^ (rv & 15)) * 8)]);
        }
#pragma unroll
        for (int dd = 0; dd < 4; dd++) oA[dd] = MFMA(av[dd], bpA, oA[dd]);
        if (doB && kbase + ch * 32 < kmaxB) {
          bf16x8 bpB = ld8(myPB16 + l15 * 136 + ch * 32 + quad * 8);
#pragma unroll
          for (int dd = 0; dd < 4; dd++) oB[dd] = MFMA(av[dd], bpB, oB[dd]);
        }
      }
    }
  }

  // ---- epilogues: each wave owns the full k-range of its 16 q-rows ----
  {
    float l = lA; l += __shfl_xor(l, 16); l += __shfl_xor(l, 32);
    float rinv = 1.0f / l;
    u16* Yp = Yb + ((size_t)b * S + qbA + l15) * E + h * 64 + quad * 4;
#pragma unroll
    for (int dd = 0; dd < 4; dd++) {
      ushort4 y;
      y.x = f2b(oA[dd][0] * rinv); y.y = f2b(oA[dd][1] * rinv);
      y.z = f2b(oA[dd][2] * rinv); y.w = f2b(oA[dd][3] * rinv);
      *reinterpret_cast<ushort4*>(Yp + dd * 16) = y;
    }
  }
  {
    float l = lB; l += __shfl_xor(l, 16); l += __shfl_xor(l, 32);
    float rinv = 1.0f / l;
    u16* Yp = Yb + ((size_t)b * S + qbB + l15) * E + h * 64 + quad * 4;
#pragma unroll
    for (int dd = 0; dd < 4; dd++) {
      ushort4 y;
      y.x = f2b(oB[dd][0] * rinv); y.y = f2b(oB[dd][1] * rinv);
      y.z = f2b(oB[dd][2] * rinv); y.w = f2b(oB[dd][3] * rinv);
      *reinterpret_cast<ushort4*>(Yp + dd * 16) = y;
    }
  }
}

// ---------------- GEMM2: out = Yb @ wpbT^T, 128x64 tile (512 blocks = 2/CU), fp32 out ----
__global__ __launch_bounds__(256) void gemm_proj(const u16* __restrict__ A, const u16* __restrict__ BT,
                                                 float* __restrict__ out) {
  constexpr int K = 1024, BK = 64;
  __shared__ __align__(16) u16 As[128 * BK];   // 16 KB
  __shared__ __align__(16) u16 Bs[64 * BK];    // 8 KB
  int tid = threadIdx.x;
  int w = tid >> 6, lane = tid & 63, quad = lane >> 4, l15 = lane & 15;
  int m0 = blockIdx.x * 128, n0 = blockIdx.y * 64;
  int mw = (w >> 1) * 64, nw = (w & 1) * 32;
  const u16* Ab = A + (size_t)m0 * K;
  const u16* Bb = BT + (size_t)n0 * K;
  f32x4 acc[4][2] = {};
  for (int k0 = 0; k0 < K; k0 += BK) {
#pragma unroll
    for (int j = 0; j < 4; j++) {
      int L = j * 256 + tid;
      int row = L >> 3, cg = (L & 7) ^ (row & 7);
      G2L16(Ab + (size_t)row * K + k0 + cg * 8, (char*)As + L * 16);
    }
#pragma unroll
    for (int j = 0; j < 2; j++) {
      int L = j * 256 + tid;
      int row = L >> 3, cg = (L & 7) ^ (row & 7);
      G2L16(Bb + (size_t)row * K + k0 + cg * 8, (char*)Bs + L * 16);
    }
    __syncthreads();
#pragma unroll
    for (int kk = 0; kk < 2; kk++) {
      int sg = ((kk << 2) | quad) ^ (l15 & 7);
      bf16x8 a[4], b[2];
#pragma unroll
      for (int i = 0; i < 4; i++) a[i] = ld8(&As[(mw + i * 16 + l15) * BK + sg * 8]);
#pragma unroll
      for (int i = 0; i < 2; i++) b[i] = ld8(&Bs[(nw + i * 16 + l15) * BK + sg * 8]);
#pragma unroll
      for (int mb = 0; mb < 4; mb++)
#pragma unroll
        for (int nb = 0; nb < 2; nb++)
          acc[mb][nb] = MFMA(a[mb], b[nb], acc[mb][nb]);
    }
    __syncthreads();
  }
#pragma unroll
  for (int mb = 0; mb < 4; mb++) {
    int m = m0 + mw + mb * 16 + quad * 4;
#pragma unroll
    for (int nb = 0; nb < 2; nb++) {
      int n = n0 + nw + nb * 16 + l15;
#pragma unroll
      for (int r = 0; r < 4; r++)
        out[(size_t)(m + r) * E + n] = acc[mb][nb][r];
    }
  }
}

extern "C" void kernel_launch(void* const* d_in, const int* in_sizes, int n_in,
                              void* d_out, int out_size, void* d_ws, size_t ws_size,
                              hipStream_t stream) {
  const float* x = (const float*)d_in[0];
  const float* w_attn = (const float*)d_in[1];
  const float* w_proj = (const float*)d_in[2];
  float* out = (float*)d_out;
  char* ws = (char*)d_ws;

  // workspace layout (bytes)
  u16* xb   = (u16*)(ws);                      // 4096*1024*2 = 8 MB
  u16* wabT = (u16*)(ws + 8388608);            // 3072*1024*2 = 6 MB
  u16* wpbT = (u16*)(ws + 14680064);           // 1024*1024*2 = 2 MB
  u16* Qb   = (u16*)(ws + 16777216);           // 8 MB
  u16* Kb   = (u16*)(ws + 25165824);           // 8 MB
  u16* VbT  = (u16*)(ws + 33554432);           // 8 MB
  u16* Yb   = (u16*)(ws + 41943040);           // 8 MB   (total 48 MB)

  prep<<<8192, 256, 0, stream>>>(x, w_attn, w_proj, xb, wabT, wpbT);
  gemm_qkv<<<dim3(Mrows / 128, N_QKV / 64), 256, 0, stream>>>(xb, wabT, Qb, Kb, VbT);
  attn<<<Bn * H * (S / 128), 256, 0, stream>>>(Qb, Kb, VbT, Yb);
  gemm_proj<<<dim3(Mrows / 128, E / 64), 256, 0, stream>>>(Yb, wpbT, out);
}

// Round 17
// 166.609 us; speedup vs baseline: 1.0364x; 1.0080x over previous
//
#include <hip/hip_runtime.h>

#define DEVI __device__ __forceinline__

typedef short bf16x8 __attribute__((ext_vector_type(8)));
typedef float f32x4 __attribute__((ext_vector_type(4)));
typedef unsigned short u16;
typedef unsigned int u32;

// Problem constants
static constexpr int Bn = 2, S = 2048, E = 1024, H = 16, D = 64;
static constexpr int Mrows = Bn * S;          // 4096
static constexpr int N_QKV = 3 * E;           // 3072

DEVI u16 f2b(float f) {
  union { float f; u32 u; } c; c.f = f;
  return (u16)((c.u + 0x7FFFu + ((c.u >> 16) & 1u)) >> 16);
}

DEVI bf16x8 ld8(const u16* p) {
  union { uint4 u; bf16x8 v; } c;
  c.u = *reinterpret_cast<const uint4*>(p);
  return c.v;
}

#define MFMA(a, b, c) __builtin_amdgcn_mfma_f32_16x16x32_bf16(a, b, c, 0, 0, 0)

// global -> LDS async copy, 16B per lane. LDS dest must be wave-uniform-base + lane*16.
#define G2L16(gptr, lptr) \
  __builtin_amdgcn_global_load_lds((const __attribute__((address_space(1))) void*)(gptr), \
                                   (__attribute__((address_space(3))) void*)(lptr), 16, 0, 0)

// ---------------- Fused prep: transposes FIRST, conv LAST (r14 order) ----------------
__global__ __launch_bounds__(256) void prep(const float* __restrict__ x,
                                            const float* __restrict__ w_attn,
                                            const float* __restrict__ w_proj,
                                            u16* __restrict__ xb, u16* __restrict__ wabT,
                                            u16* __restrict__ wpbT) {
  __shared__ float t[32][33];
  int blk = blockIdx.x, tid = threadIdx.x;
  if (blk >= 4096) {
    int i = (blk - 4096) * 256 + tid;          // n4 = 4096*1024/4 = 1048576
    float4 f = reinterpret_cast<const float4*>(x)[i];
    ushort4 u;
    u.x = f2b(f.x); u.y = f2b(f.y); u.z = f2b(f.z); u.w = f2b(f.w);
    reinterpret_cast<ushort4*>(xb)[i] = u;
    return;
  }
  const float* in; u16* out; int R, C, bx, by;
  if (blk < 3072) {
    in = w_attn; out = wabT; R = E; C = N_QKV;  // 96 x 32 tiles
    bx = (blk % 96) * 32; by = (blk / 96) * 32;
  } else {
    int q = blk - 3072;                         // 32 x 32 tiles
    in = w_proj; out = wpbT; R = E; C = E;
    bx = (q % 32) * 32; by = (q / 32) * 32;
  }
  int tx = tid & 31, ty = tid >> 5;             // 32 x 8
#pragma unroll
  for (int k = 0; k < 32; k += 8)
    t[ty + k][tx] = in[(size_t)(by + ty + k) * C + bx + tx];
  __syncthreads();
#pragma unroll
  for (int k = 0; k < 32; k += 8)
    out[(size_t)(bx + ty + k) * R + by + tx] = f2b(t[tx][ty + k]);
}

// ---------------- GEMM1: qkv = xb @ wabT^T, 128x64 tile, BK=64, XOR swizzle (r14) ---------
// Q pre-scaled by log2e/8 so attn scores arrive in log2 domain (exp2 = bare v_exp_f32).
__global__ __launch_bounds__(256) void gemm_qkv(const u16* __restrict__ A, const u16* __restrict__ BT,
                                                u16* __restrict__ Qb, u16* __restrict__ Kb,
                                                u16* __restrict__ VbT) {
  constexpr int K = 1024, BK = 64;
  __shared__ __align__(16) u16 As[128 * BK];   // 16 KB, swizzled rows of 8 16B-groups
  __shared__ __align__(16) u16 Bs[64 * BK];    // 8 KB
  int tid = threadIdx.x;
  int w = tid >> 6, lane = tid & 63, quad = lane >> 4, l15 = lane & 15;
  int m0 = blockIdx.x * 128, n0 = blockIdx.y * 64;
  int mw = (w >> 1) * 64, nw = (w & 1) * 32;   // wave-tile 64x32
  const u16* Ab = A + (size_t)m0 * K;
  const u16* Bb = BT + (size_t)n0 * K;
  f32x4 acc[4][2] = {};
  for (int k0 = 0; k0 < K; k0 += BK) {
#pragma unroll
    for (int j = 0; j < 4; j++) {
      int L = j * 256 + tid;
      int row = L >> 3, cg = (L & 7) ^ (row & 7);
      G2L16(Ab + (size_t)row * K + k0 + cg * 8, (char*)As + L * 16);
    }
#pragma unroll
    for (int j = 0; j < 2; j++) {
      int L = j * 256 + tid;
      int row = L >> 3, cg = (L & 7) ^ (row & 7);
      G2L16(Bb + (size_t)row * K + k0 + cg * 8, (char*)Bs + L * 16);
    }
    __syncthreads();
#pragma unroll
    for (int kk = 0; kk < 2; kk++) {
      int sg = ((kk << 2) | quad) ^ (l15 & 7);   // swizzled 16B-group for this lane
      bf16x8 a[4], b[2];
#pragma unroll
      for (int i = 0; i < 4; i++) a[i] = ld8(&As[(mw + i * 16 + l15) * BK + sg * 8]);
#pragma unroll
      for (int i = 0; i < 2; i++) b[i] = ld8(&Bs[(nw + i * 16 + l15) * BK + sg * 8]);
#pragma unroll
      for (int mb = 0; mb < 4; mb++)
#pragma unroll
        for (int nb = 0; nb < 2; nb++)
          acc[mb][nb] = MFMA(a[mb], b[nb], acc[mb][nb]);
    }
    __syncthreads();
  }
#pragma unroll
  for (int mb = 0; mb < 4; mb++) {
    int m = m0 + mw + mb * 16 + quad * 4;      // rows m..m+3 (tiles never straddle batch)
    int b = m >> 11, s = m & 2047;
#pragma unroll
    for (int nb = 0; nb < 2; nb++) {
      int n = n0 + nw + nb * 16 + l15;
      int sec = n >> 10, e = n & 1023, h = e >> 6, d = e & 63;
      int bh = b * H + h;
      if (sec == 0) {
#pragma unroll
        for (int r = 0; r < 4; r++)
          Qb[((size_t)bh * S + s + r) * D + d] = f2b(acc[mb][nb][r] * 0.1803368801111244f);
      } else if (sec == 1) {
#pragma unroll
        for (int r = 0; r < 4; r++)
          Kb[((size_t)bh * S + s + r) * D + d] = f2b(acc[mb][nb][r]);
      } else {
        ushort4 v;
        v.x = f2b(acc[mb][nb][0]); v.y = f2b(acc[mb][nb][1]);
        v.z = f2b(acc[mb][nb][2]); v.w = f2b(acc[mb][nb][3]);
        *reinterpret_cast<ushort4*>(VbT + ((size_t)bh * D + d) * S + s) = v;
      }
    }
  }
}

// ---------------- Flash attention: UNPAIRED q-tiles, 3 blocks/CU ----------------
// r15/r16's paired blocks capped co-residency at 2 blocks/CU (512-block grid) = 8 of 32
// waves; issue-slot accounting shows ~20% utilization -- latency-bound, needs waves.
// Un-paired: 1024 blocks (bh, qt), heavy-first (qt = 31 - blk>>5), single P buffer ->
// LDS 49.8KB -> 3 blocks/CU = 12 waves/CU, 4 block-generations give dynamic backfill
// against causal imbalance. Same-bh -> same-XCD preserved (blk%8 == bh%8).
// Fixed-max softmax (m==0, log2-domain scores); lean exp2+perm pack (r15).
__global__ __launch_bounds__(256, 3) void attn(const u16* __restrict__ Qb, const u16* __restrict__ Kb,
                                               const u16* __restrict__ VbT, u16* __restrict__ Yb) {
  __shared__ __align__(16) u16 Ks[128 * 64];    // swizzled: (row, cg) at row*64 + (cg^(row&7))*8
  __shared__ __align__(16) u16 Vs[64 * 128];    // swizzled: (d, cg) at d*128 + (cg^(d&15))*8
  __shared__ __align__(16) u32 Ps[4][16 * 68];  // per-wave P[q=16][k=128] bf16, stride 68 u32
  int w = threadIdx.x >> 6, lane = threadIdx.x & 63, quad = lane >> 4, l15 = lane & 15;
  int bh = blockIdx.x & 31, qt = 31 - (blockIdx.x >> 5);   // heavy q-tiles first
  int b = bh >> 4, h = bh & 15;
  int nc = (qt + 2) >> 1;            // staged 128-key chunks

  const u16* Kbh = Kb + (size_t)bh * S * D;
  const u16* Vbh = VbT + (size_t)bh * D * S;
  u32* myP = &Ps[w][0];
  const u16* myP16 = (const u16*)myP;
  int prow = l15 * 68 + quad * 2;    // u32 index for this lane's P writes

  int q_base = qt * 64 + w * 16;
  int qrow = q_base + l15;
  int kmax = q_base + 16;            // causal: this wave needs keys [0, kmax)

  const u16* Qp = Qb + ((size_t)bh * S + qrow) * D + quad * 8;
  bf16x8 bq0 = ld8(Qp), bq1 = ld8(Qp + 32);

  float lpart = 0.f;
  f32x4 o[4] = {};

  for (int c = 0; c < nc; c++) {
    int kbase = c * 128;
    __syncthreads();                 // previous chunk's readers done
    // ---- cooperative staging: K tile (16KB) ----
    const u16* Kg = Kbh + (size_t)kbase * D;
#pragma unroll
    for (int j = 0; j < 4; j++) {
      int L = (w * 4 + j) * 64 + lane;
      int row = L >> 3, cg = (L & 7) ^ (row & 7);
      G2L16(Kg + (size_t)row * 64 + cg * 8, (char*)Ks + L * 16);
    }
    // ---- cooperative staging: V^T tile (16KB) ----
    const u16* Vg = Vbh + kbase;
#pragma unroll
    for (int j = 0; j < 4; j++) {
      int L = (w * 4 + j) * 64 + lane;
      int row = L >> 4, cg = (L & 15) ^ (row & 15);
      G2L16(Vg + (size_t)row * S + cg * 8, (char*)Vs + L * 16);
    }
    __syncthreads();                 // staging visible (barrier drains vmcnt)

    // ---- QK^T + exp2 + perm-pack into wave-private P ----
#pragma unroll
    for (int mb = 0; mb < 8; mb++) {
      int kb = kbase + mb * 16;
      u32 pa = 0, pb = 0;
      if (kb < kmax) {               // wave-uniform
        int row = mb * 16 + l15;
        bf16x8 ak0 = ld8(&Ks[row * 64 + ((quad ^ (row & 7)) * 8)]);
        bf16x8 ak1 = ld8(&Ks[row * 64 + (((quad + 4) ^ (row & 7)) * 8)]);
        f32x4 z = {};
        z = MFMA(ak0, bq0, z);
        z = MFMA(ak1, bq1, z);
        if (kb == q_base) {          // diagonal subtile: mask k > q
#pragma unroll
          for (int r = 0; r < 4; r++)
            if (quad * 4 + r > l15) z[r] = -1e30f;
        }
        float p0 = __builtin_amdgcn_exp2f(z[0]);
        float p1 = __builtin_amdgcn_exp2f(z[1]);
        float p2 = __builtin_amdgcn_exp2f(z[2]);
        float p3 = __builtin_amdgcn_exp2f(z[3]);
        lpart += (p0 + p1) + (p2 + p3);
        union { float f; u32 u; } c0, c1, c2, c3;
        c0.f = p0; c1.f = p1; c2.f = p2; c3.f = p3;
        pa = __builtin_amdgcn_perm(c1.u + 0x8000u, c0.u + 0x8000u, 0x07060302u);
        pb = __builtin_amdgcn_perm(c3.u + 0x8000u, c2.u + 0x8000u, 0x07060302u);
      }
      uint2 pw; pw.x = pa; pw.y = pb;
      *reinterpret_cast<uint2*>(&myP[prow + mb * 8]) = pw;   // ds_write_b64
    }
    // ---- O^T += V^T · P^T per 32-key chunk ----
#pragma unroll
    for (int ch = 0; ch < 4; ch++) {
      if (kbase + ch * 32 < kmax) {  // wave-uniform
        bf16x8 bp = ld8(myP16 + l15 * 136 + ch * 32 + quad * 8);
#pragma unroll
        for (int dd = 0; dd < 4; dd++) {
          int rv = dd * 16 + l15;
          bf16x8 av = ld8(&Vs[rv * 128 + (((ch * 4 + quad) ^ (rv & 15)) * 8)]);
          o[dd] = MFMA(av, bp, o[dd]);
        }
      }
    }
  }

  // ---- epilogue: each wave owns the full k-range of its 16 q-rows ----
  float l = lpart;
  l += __shfl_xor(l, 16);
  l += __shfl_xor(l, 32);
  float rinv = 1.0f / l;
  u16* Yp = Yb + ((size_t)b * S + qrow) * E + h * 64 + quad * 4;
#pragma unroll
  for (int dd = 0; dd < 4; dd++) {
    ushort4 y;
    y.x = f2b(o[dd][0] * rinv); y.y = f2b(o[dd][1] * rinv);
    y.z = f2b(o[dd][2] * rinv); y.w = f2b(o[dd][3] * rinv);
    *reinterpret_cast<ushort4*>(Yp + dd * 16) = y;
  }
}

// ---------------- GEMM2: out = Yb @ wpbT^T, 128x64 tile (512 blocks = 2/CU), fp32 out ----
__global__ __launch_bounds__(256) void gemm_proj(const u16* __restrict__ A, const u16* __restrict__ BT,
                                                 float* __restrict__ out) {
  constexpr int K = 1024, BK = 64;
  __shared__ __align__(16) u16 As[128 * BK];   // 16 KB
  __shared__ __align__(16) u16 Bs[64 * BK];    // 8 KB
  int tid = threadIdx.x;
  int w = tid >> 6, lane = tid & 63, quad = lane >> 4, l15 = lane & 15;
  int m0 = blockIdx.x * 128, n0 = blockIdx.y * 64;
  int mw = (w >> 1) * 64, nw = (w & 1) * 32;
  const u16* Ab = A + (size_t)m0 * K;
  const u16* Bb = BT + (size_t)n0 * K;
  f32x4 acc[4][2] = {};
  for (int k0 = 0; k0 < K; k0 += BK) {
#pragma unroll
    for (int j = 0; j < 4; j++) {
      int L = j * 256 + tid;
      int row = L >> 3, cg = (L & 7) ^ (row & 7);
      G2L16(Ab + (size_t)row * K + k0 + cg * 8, (char*)As + L * 16);
    }
#pragma unroll
    for (int j = 0; j < 2; j++) {
      int L = j * 256 + tid;
      int row = L >> 3, cg = (L & 7) ^ (row & 7);
      G2L16(Bb + (size_t)row * K + k0 + cg * 8, (char*)Bs + L * 16);
    }
    __syncthreads();
#pragma unroll
    for (int kk = 0; kk < 2; kk++) {
      int sg = ((kk << 2) | quad) ^ (l15 & 7);
      bf16x8 a[4], b[2];
#pragma unroll
      for (int i = 0; i < 4; i++) a[i] = ld8(&As[(mw + i * 16 + l15) * BK + sg * 8]);
#pragma unroll
      for (int i = 0; i < 2; i++) b[i] = ld8(&Bs[(nw + i * 16 + l15) * BK + sg * 8]);
#pragma unroll
      for (int mb = 0; mb < 4; mb++)
#pragma unroll
        for (int nb = 0; nb < 2; nb++)
          acc[mb][nb] = MFMA(a[mb], b[nb], acc[mb][nb]);
    }
    __syncthreads();
  }
#pragma unroll
  for (int mb = 0; mb < 4; mb++) {
    int m = m0 + mw + mb * 16 + quad * 4;
#pragma unroll
    for (int nb = 0; nb < 2; nb++) {
      int n = n0 + nw + nb * 16 + l15;
#pragma unroll
      for (int r = 0; r < 4; r++)
        out[(size_t)(m + r) * E + n] = acc[mb][nb][r];
    }
  }
}

extern "C" void kernel_launch(void* const* d_in, const int* in_sizes, int n_in,
                              void* d_out, int out_size, void* d_ws, size_t ws_size,
                              hipStream_t stream) {
  const float* x = (const float*)d_in[0];
  const float* w_attn = (const float*)d_in[1];
  const float* w_proj = (const float*)d_in[2];
  float* out = (float*)d_out;
  char* ws = (char*)d_ws;

  // workspace layout (bytes)
  u16* xb   = (u16*)(ws);                      // 4096*1024*2 = 8 MB
  u16* wabT = (u16*)(ws + 8388608);            // 3072*1024*2 = 6 MB
  u16* wpbT = (u16*)(ws + 14680064);           // 1024*1024*2 = 2 MB
  u16* Qb   = (u16*)(ws + 16777216);           // 8 MB
  u16* Kb   = (u16*)(ws + 25165824);           // 8 MB
  u16* VbT  = (u16*)(ws + 33554432);           // 8 MB
  u16* Yb   = (u16*)(ws + 41943040);           // 8 MB   (total 48 MB)

  prep<<<8192, 256, 0, stream>>>(x, w_attn, w_proj, xb, wabT, wpbT);
  gemm_qkv<<<dim3(Mrows / 128, N_QKV / 64), 256, 0, stream>>>(xb, wabT, Qb, Kb, VbT);
  attn<<<Bn * H * (S / 64), 256, 0, stream>>>(Qb, Kb, VbT, Yb);
  gemm_proj<<<dim3(Mrows / 128, E / 64), 256, 0, stream>>>(Yb, wpbT, out);
}